// Round 1
// baseline (491.247 us; speedup 1.0000x reference)
//
#include <hip/hip_runtime.h>
#include <math.h>

#define N_NODES 50000
#define E_EDGES 500000
#define D 32
#define ED 16
// msg layout per wave: [0..31]=h[row], [32..63]=Q@h[col], [64..79]=edge_attr, [80..111]=hidden
#define MSG_LEN 112

__global__ __launch_bounds__(256) void edge_kernel(
    const float* __restrict__ h, const float* __restrict__ edge_attr,
    const float* __restrict__ Q, const float* __restrict__ W1,
    const float* __restrict__ b1, const float* __restrict__ W2,
    const float* __restrict__ b2, const int* __restrict__ eidx,
    float* __restrict__ agg)
{
    const int lane = threadIdx.x & 63;
    const int wib  = threadIdx.x >> 6;                 // wave in block (0..3)
    const int gwave = blockIdx.x * 4 + wib;
    const int nwaves = gridDim.x * 4;

    const int o   = lane & 31;   // output unit this lane owns
    const int hh  = lane >> 5;   // which half of the reduction dim
    const int g   = lane >> 3;   // Q row group (0..7)
    const int sub = lane & 7;    // Q col chunk within group

    // --- weight columns in registers (W1: 80x32, W2: 32x32) ---
    float w1c[40];
#pragma unroll
    for (int i = 0; i < 40; ++i) w1c[i] = W1[(hh * 40 + i) * D + o];
    float w2c[16];
#pragma unroll
    for (int i = 0; i < 16; ++i) w2c[i] = W2[(hh * 16 + i) * D + o];
    const float b1o = b1[o];
    const float b2o = b2[o];

    __shared__ float msg_s[4][MSG_LEN];
    float* m = msg_s[wib];

    for (int e = gwave; e < E_EDGES; e += nwaves) {
        const int row = eidx[e];
        const int col = eidx[E_EDGES + e];

        // h[col] chunk matching this lane's Q columns (j = sub*4 .. +3)
        const float4 hc = *reinterpret_cast<const float4*>(h + (size_t)col * D + sub * 4);

        const float* qe = Q + (size_t)e * (D * D);
        float acc[4];
#pragma unroll
        for (int k = 0; k < 4; ++k) {
            const float4 q = *reinterpret_cast<const float4*>(qe + k * 256 + lane * 4);
            acc[k] = q.x * hc.x + q.y * hc.y + q.z * hc.z + q.w * hc.w;
        }
        // reduce partial dots across the 8 lanes of each row group
#pragma unroll
        for (int mm = 1; mm <= 4; mm <<= 1) {
#pragma unroll
            for (int k = 0; k < 4; ++k) acc[k] += __shfl_xor(acc[k], mm);
        }

        // stage msg_input = [h[row] | Q@h[col] | edge_attr]
        if (lane < D)               m[lane] = h[(size_t)row * D + lane];
        else if (lane < D + ED)     m[64 + (lane - D)] = edge_attr[(size_t)e * ED + (lane - D)];
        if (sub == 0) {
#pragma unroll
            for (int k = 0; k < 4; ++k) m[D + k * 8 + g] = acc[k];
        }
        asm volatile("s_waitcnt lgkmcnt(0)" ::: "memory");

        // hidden[o] = relu(msg . W1[:,o] + b1[o]), split over hh halves
        float s = 0.f;
        const float4* mv4 = reinterpret_cast<const float4*>(m + hh * 40);
#pragma unroll
        for (int i4 = 0; i4 < 10; ++i4) {
            const float4 mv = mv4[i4];
            s = fmaf(mv.x, w1c[4 * i4 + 0], s);
            s = fmaf(mv.y, w1c[4 * i4 + 1], s);
            s = fmaf(mv.z, w1c[4 * i4 + 2], s);
            s = fmaf(mv.w, w1c[4 * i4 + 3], s);
        }
        s += __shfl_xor(s, 32);
        s = fmaxf(s + b1o, 0.f);

        // park hidden in LDS for the second layer
        if (lane < D) m[80 + lane] = s;
        asm volatile("s_waitcnt lgkmcnt(0)" ::: "memory");

        float tv = 0.f;
        const float4* hv4 = reinterpret_cast<const float4*>(m + 80 + hh * 16);
#pragma unroll
        for (int i4 = 0; i4 < 4; ++i4) {
            const float4 hv = hv4[i4];
            tv = fmaf(hv.x, w2c[4 * i4 + 0], tv);
            tv = fmaf(hv.y, w2c[4 * i4 + 1], tv);
            tv = fmaf(hv.z, w2c[4 * i4 + 2], tv);
            tv = fmaf(hv.w, w2c[4 * i4 + 3], tv);
        }
        tv += __shfl_xor(tv, 32);
        tv += b2o;

        if (lane < D) atomicAdd(&agg[(size_t)row * D + lane], tv);
    }
}

__global__ __launch_bounds__(256) void node_kernel(
    const float* __restrict__ h, const float* __restrict__ agg,
    const float* __restrict__ Wd1, const float* __restrict__ bd1,
    const float* __restrict__ ln_g, const float* __restrict__ ln_b,
    const float* __restrict__ Wd2, const float* __restrict__ bd2,
    float* __restrict__ out)
{
    __shared__ float sWd1[64 * 32];
    __shared__ float sWd2[32 * 32];
    __shared__ float xbuf[4][64];

    for (int i = threadIdx.x; i < 64 * 32; i += 256) sWd1[i] = Wd1[i];
    for (int i = threadIdx.x; i < 32 * 32; i += 256) sWd2[i] = Wd2[i];
    __syncthreads();

    const int tid  = blockIdx.x * 256 + threadIdx.x;
    const int n    = tid >> 5;
    const int o    = tid & 31;
    const int wib  = threadIdx.x >> 6;
    const int lane = threadIdx.x & 63;
    if (n >= N_NODES) return;

    const float* hn = h   + (size_t)n * D;
    const float* an = agg + (size_t)n * D;

    // x[o] = [h | agg] . Wd1[:,o] + bd1[o]
    float x = bd1[o];
#pragma unroll
    for (int k4 = 0; k4 < 8; ++k4) {
        const float4 hv = *reinterpret_cast<const float4*>(hn + k4 * 4);
        x = fmaf(hv.x, sWd1[(k4 * 4 + 0) * 32 + o], x);
        x = fmaf(hv.y, sWd1[(k4 * 4 + 1) * 32 + o], x);
        x = fmaf(hv.z, sWd1[(k4 * 4 + 2) * 32 + o], x);
        x = fmaf(hv.w, sWd1[(k4 * 4 + 3) * 32 + o], x);
    }
#pragma unroll
    for (int k4 = 0; k4 < 8; ++k4) {
        const float4 av = *reinterpret_cast<const float4*>(an + k4 * 4);
        x = fmaf(av.x, sWd1[(32 + k4 * 4 + 0) * 32 + o], x);
        x = fmaf(av.y, sWd1[(32 + k4 * 4 + 1) * 32 + o], x);
        x = fmaf(av.z, sWd1[(32 + k4 * 4 + 2) * 32 + o], x);
        x = fmaf(av.w, sWd1[(32 + k4 * 4 + 3) * 32 + o], x);
    }

    // LayerNorm over the 32 lanes of this node
    float mu = x;
#pragma unroll
    for (int mm = 1; mm <= 16; mm <<= 1) mu += __shfl_xor(mu, mm);
    mu *= (1.0f / 32.0f);
    const float dx = x - mu;
    float var = dx * dx;
#pragma unroll
    for (int mm = 1; mm <= 16; mm <<= 1) var += __shfl_xor(var, mm);
    var *= (1.0f / 32.0f);
    float xs = dx * rsqrtf(var + 1e-5f);
    xs = xs * ln_g[o] + ln_b[o];
    // SiLU
    xs = xs / (1.0f + __expf(-xs));

    xbuf[wib][lane] = xs;
    asm volatile("s_waitcnt lgkmcnt(0)" ::: "memory");

    // y[o] = xs . Wd2[:,o] + bd2[o]
    float y = bd2[o];
    const float* xb = &xbuf[wib][lane & 32];
#pragma unroll
    for (int k4 = 0; k4 < 8; ++k4) {
        const float4 xv = *reinterpret_cast<const float4*>(xb + k4 * 4);
        y = fmaf(xv.x, sWd2[(k4 * 4 + 0) * 32 + o], y);
        y = fmaf(xv.y, sWd2[(k4 * 4 + 1) * 32 + o], y);
        y = fmaf(xv.z, sWd2[(k4 * 4 + 2) * 32 + o], y);
        y = fmaf(xv.w, sWd2[(k4 * 4 + 3) * 32 + o], y);
    }
    out[(size_t)n * D + o] = tanhf(y);
}

extern "C" void kernel_launch(void* const* d_in, const int* in_sizes, int n_in,
                              void* d_out, int out_size, void* d_ws, size_t ws_size,
                              hipStream_t stream) {
    const float* h         = (const float*)d_in[1];
    const float* edge_attr = (const float*)d_in[2];
    const float* Q         = (const float*)d_in[3];
    const float* W1        = (const float*)d_in[4];
    const float* b1        = (const float*)d_in[5];
    const float* W2        = (const float*)d_in[6];
    const float* b2        = (const float*)d_in[7];
    const float* Wd1       = (const float*)d_in[8];
    const float* bd1       = (const float*)d_in[9];
    const float* ln_g      = (const float*)d_in[10];
    const float* ln_b      = (const float*)d_in[11];
    const float* Wd2       = (const float*)d_in[12];
    const float* bd2       = (const float*)d_in[13];
    const int*   eidx      = (const int*)d_in[14];

    float* agg = (float*)d_ws;
    hipMemsetAsync(agg, 0, (size_t)N_NODES * D * sizeof(float), stream);

    edge_kernel<<<2048, 256, 0, stream>>>(h, edge_attr, Q, W1, b1, W2, b2, eidx, agg);
    node_kernel<<<(N_NODES * D + 255) / 256, 256, 0, stream>>>(
        h, agg, Wd1, bd1, ln_g, ln_b, Wd2, bd2, (float*)d_out);
}